// Round 2
// baseline (344.432 us; speedup 1.0000x reference)
//
#include <hip/hip_runtime.h>
#include <hip/hip_bf16.h>

// MHA block: B=2, S=2048, D_MODEL=512, H=8, D_K=64.
// Reference dtype ambiguous (f32 reference, bf16-labeled test) -> runtime dtype
// detection + conversion to a bf16 internal pipeline:
//   detect -> convert inputs to bf16 ws -> Q/K/V proj GEMMs -> flash attention
//   -> output proj GEMM (stores f32 or bf16 per detected flag).

typedef __attribute__((ext_vector_type(8))) short short8;   // 8 bf16 (4 VGPRs)
typedef __attribute__((ext_vector_type(4))) float f32x4;    // MFMA 16x16 accum

#define DM 512
#define SEQ 2048
#define NROW 4096   // B * SEQ

__device__ __forceinline__ short f2bf_bits(float f) {
    __hip_bfloat16 h = __float2bfloat16(f);
    union { __hip_bfloat16 h; short s; } u; u.h = h; return u.s;
}
__device__ __forceinline__ float bf_bits2f(short s) {
    union { short s; __hip_bfloat16 h; } u; u.s = s; return __bfloat162float(u.h);
}

// ---------------------------------------------------------------------------
// Dtype detection: look at first 1024 words of q. If inputs are bf16, the low
// 16 bits of each word are a bf16 N(0,1) sample -> magnitude bits concentrated
// in [0x3000, 0x4400). If f32, low 16 bits are uniform mantissa bits (~16% in
// range). flag: 1 = f32 inputs/outputs, 0 = bf16.
__global__ void detect_dtype(const unsigned int* __restrict__ q, int* __restrict__ flag) {
    __shared__ int cnt;
    if (threadIdx.x == 0) cnt = 0;
    __syncthreads();
    int local = 0;
    for (int i = threadIdx.x; i < 1024; i += 256) {
        unsigned int lo = q[i] & 0x7FFFu;
        if (lo >= 0x3000u && lo < 0x4400u) local++;
    }
    atomicAdd(&cnt, local);
    __syncthreads();
    if (threadIdx.x == 0) *flag = (cnt < 512) ? 1 : 0;
}

// Convert one tensor to bf16 scratch (f32->bf16 convert, or bf16 passthrough).
__global__ void convert_to_bf16(const void* __restrict__ src, short* __restrict__ dst,
                                int n, const int* __restrict__ flag) {
    const int f32mode = *flag;
    int i = blockIdx.x * blockDim.x + threadIdx.x;
    const int stride = gridDim.x * blockDim.x;
    if (f32mode) {
        const float* s = (const float*)src;
        for (; i < n; i += stride) dst[i] = f2bf_bits(s[i]);
    } else {
        const short* s = (const short*)src;
        for (; i < n; i += stride) dst[i] = s[i];
    }
}

// ---------------------------------------------------------------------------
// C[m][n] = sum_k A[m][k] * W[n][k] + bias[n].  A: [M,512], W: [512,512].
// One wave per 16(M) x 64(N) tile. Verified gfx950 16x16x32 bf16 layouts:
//   A-frag: m=lane&15, k=quad*8+j ; B-frag: n=lane&15, k=quad*8+j ;
//   C:      row=quad*4+r, col=lane&15.
// outFlag == nullptr -> bf16 out; else *outFlag selects f32 (1) / bf16 (0).
__global__ __launch_bounds__(64) void gemm_bias_bt(
    const short* __restrict__ A, const short* __restrict__ W,
    const short* __restrict__ bias, void* __restrict__ Cout,
    const int* __restrict__ outFlag)
{
    const int lane = threadIdx.x;
    const int rc   = lane & 15;
    const int quad = lane >> 4;
    const int m0 = blockIdx.x * 16;
    const int n0 = blockIdx.y * 64;

    f32x4 acc[4];
    #pragma unroll
    for (int nt = 0; nt < 4; nt++) acc[nt] = f32x4{0.f, 0.f, 0.f, 0.f};

    const short* Arow = A + (size_t)(m0 + rc) * DM + quad * 8;
    for (int k0 = 0; k0 < DM; k0 += 32) {
        short8 a = *(const short8*)(Arow + k0);
        #pragma unroll
        for (int nt = 0; nt < 4; nt++) {
            short8 b = *(const short8*)(W + (size_t)(n0 + nt * 16 + rc) * DM + k0 + quad * 8);
            acc[nt] = __builtin_amdgcn_mfma_f32_16x16x32_bf16(a, b, acc[nt], 0, 0, 0);
        }
    }

    const bool f32out = (outFlag != nullptr) && (*outFlag != 0);
    #pragma unroll
    for (int nt = 0; nt < 4; nt++) {
        const int col = n0 + nt * 16 + rc;
        const float bv = bf_bits2f(bias[col]);
        #pragma unroll
        for (int r = 0; r < 4; r++) {
            const int row = m0 + quad * 4 + r;
            const size_t idx = (size_t)row * DM + col;
            const float val = acc[nt][r] + bv;
            if (f32out) ((float*)Cout)[idx] = val;
            else        ((short*)Cout)[idx] = f2bf_bits(val);
        }
    }
}

// ---------------------------------------------------------------------------
// Flash attention: one wave per (b,h, 16-query tile). Q,K,V: [4096,512] bf16,
// head at col h*64. Key tiles of 32; QK^T via 4 MFMAs; online softmax per row;
// P through LDS (C-layout -> A-operand layout); PV via 4 MFMAs.
__global__ __launch_bounds__(64) void attn_kernel(
    const short* __restrict__ Q, const short* __restrict__ K,
    const short* __restrict__ V, short* __restrict__ O)
{
    const int lane = threadIdx.x;
    const int rc   = lane & 15;
    const int quad = lane >> 4;
    const int bh = blockIdx.y;                 // b*8 + h
    const size_t base = (size_t)(bh >> 3) * SEQ * DM + (size_t)(bh & 7) * 64;
    const int q0 = blockIdx.x * 16;

    const short* Qb = Q + base;
    const short* Kb = K + base;
    const short* Vb = V + base;

    short8 qa0 = *(const short8*)(Qb + (size_t)(q0 + rc) * DM + quad * 8);
    short8 qa1 = *(const short8*)(Qb + (size_t)(q0 + rc) * DM + 32 + quad * 8);

    f32x4 o[4];
    #pragma unroll
    for (int dt = 0; dt < 4; dt++) o[dt] = f32x4{0.f, 0.f, 0.f, 0.f};
    float mrow[4], lrow[4];
    #pragma unroll
    for (int r = 0; r < 4; r++) { mrow[r] = -1e30f; lrow[r] = 0.f; }

    __shared__ __align__(16) short Plds[16 * 32];
    const float scale = 0.125f;  // 1/sqrt(64)

    for (int k0 = 0; k0 < SEQ; k0 += 32) {
        const short* Kr0 = Kb + (size_t)(k0 + rc) * DM + quad * 8;
        const short* Kr1 = Kb + (size_t)(k0 + 16 + rc) * DM + quad * 8;
        short8 kb0 = *(const short8*)(Kr0);
        short8 kb1 = *(const short8*)(Kr0 + 32);
        short8 kb2 = *(const short8*)(Kr1);
        short8 kb3 = *(const short8*)(Kr1 + 32);
        f32x4 s0 = f32x4{0.f, 0.f, 0.f, 0.f};
        f32x4 s1 = f32x4{0.f, 0.f, 0.f, 0.f};
        s0 = __builtin_amdgcn_mfma_f32_16x16x32_bf16(qa0, kb0, s0, 0, 0, 0);
        s0 = __builtin_amdgcn_mfma_f32_16x16x32_bf16(qa1, kb1, s0, 0, 0, 0);
        s1 = __builtin_amdgcn_mfma_f32_16x16x32_bf16(qa0, kb2, s1, 0, 0, 0);
        s1 = __builtin_amdgcn_mfma_f32_16x16x32_bf16(qa1, kb3, s1, 0, 0, 0);

        #pragma unroll
        for (int r = 0; r < 4; r++) {
            float v0 = s0[r] * scale;
            float v1 = s1[r] * scale;
            float mx = fmaxf(v0, v1);
            #pragma unroll
            for (int off = 1; off < 16; off <<= 1)
                mx = fmaxf(mx, __shfl_xor(mx, off, 16));
            float mnew  = fmaxf(mrow[r], mx);
            float alpha = __expf(mrow[r] - mnew);
            float p0 = __expf(v0 - mnew);
            float p1 = __expf(v1 - mnew);
            float ps = p0 + p1;
            #pragma unroll
            for (int off = 1; off < 16; off <<= 1)
                ps += __shfl_xor(ps, off, 16);
            lrow[r] = lrow[r] * alpha + ps;
            mrow[r] = mnew;
            o[0][r] *= alpha; o[1][r] *= alpha; o[2][r] *= alpha; o[3][r] *= alpha;
            Plds[(quad * 4 + r) * 32 + rc]      = f2bf_bits(p0);
            Plds[(quad * 4 + r) * 32 + 16 + rc] = f2bf_bits(p1);
        }
        __syncthreads();
        short8 pa = *(const short8*)(&Plds[rc * 32 + quad * 8]);

        #pragma unroll
        for (int dt = 0; dt < 4; dt++) {
            short8 vb;
            #pragma unroll
            for (int j = 0; j < 8; j++)
                vb[j] = Vb[(size_t)(k0 + quad * 8 + j) * DM + dt * 16 + rc];
            o[dt] = __builtin_amdgcn_mfma_f32_16x16x32_bf16(pa, vb, o[dt], 0, 0, 0);
        }
        __syncthreads();
    }

    #pragma unroll
    for (int dt = 0; dt < 4; dt++) {
        #pragma unroll
        for (int r = 0; r < 4; r++) {
            float val = o[dt][r] / lrow[r];
            O[base + (size_t)(q0 + quad * 4 + r) * DM + dt * 16 + rc] = f2bf_bits(val);
        }
    }
}

// ---------------------------------------------------------------------------
extern "C" void kernel_launch(void* const* d_in, const int* in_sizes, int n_in,
                              void* d_out, int out_size, void* d_ws, size_t ws_size,
                              hipStream_t stream) {
    // setup_inputs order: q, v, k, w_q, b_q, w_k, b_k, w_v, b_v, w_o, b_o
    char* ws = (char*)d_ws;
    const size_t SEQB = (size_t)NROW * DM * sizeof(short);  // 4 MB
    const size_t WB   = (size_t)DM * DM * sizeof(short);    // 512 KB
    const size_t BB   = (size_t)DM * sizeof(short);         // 1 KB

    int*   flag = (int*)ws;
    size_t off = 256;
    short* qc = (short*)(ws + off); off += SEQB;
    short* vc = (short*)(ws + off); off += SEQB;
    short* kc = (short*)(ws + off); off += SEQB;
    short* wq = (short*)(ws + off); off += WB;
    short* wk = (short*)(ws + off); off += WB;
    short* wv = (short*)(ws + off); off += WB;
    short* wo = (short*)(ws + off); off += WB;
    short* bq = (short*)(ws + off); off += BB;
    short* bk = (short*)(ws + off); off += BB;
    short* bv = (short*)(ws + off); off += BB;
    short* bo = (short*)(ws + off); off += BB;
    off = (off + 255) & ~(size_t)255;
    short* Qp = (short*)(ws + off); off += SEQB;
    short* Kp = (short*)(ws + off); off += SEQB;
    short* Vp = (short*)(ws + off); off += SEQB;
    short* Xp = (short*)(ws + off); off += SEQB;

    detect_dtype<<<1, 256, 0, stream>>>((const unsigned int*)d_in[0], flag);

    const int nBig = NROW * DM, nW = DM * DM, nB = DM;
    convert_to_bf16<<<512, 256, 0, stream>>>(d_in[0], qc, nBig, flag);
    convert_to_bf16<<<512, 256, 0, stream>>>(d_in[1], vc, nBig, flag);
    convert_to_bf16<<<512, 256, 0, stream>>>(d_in[2], kc, nBig, flag);
    convert_to_bf16<<<128, 256, 0, stream>>>(d_in[3], wq, nW, flag);
    convert_to_bf16<<<128, 256, 0, stream>>>(d_in[5], wk, nW, flag);
    convert_to_bf16<<<128, 256, 0, stream>>>(d_in[7], wv, nW, flag);
    convert_to_bf16<<<128, 256, 0, stream>>>(d_in[9], wo, nW, flag);
    convert_to_bf16<<<2, 256, 0, stream>>>(d_in[4],  bq, nB, flag);
    convert_to_bf16<<<2, 256, 0, stream>>>(d_in[6],  bk, nB, flag);
    convert_to_bf16<<<2, 256, 0, stream>>>(d_in[8],  bv, nB, flag);
    convert_to_bf16<<<2, 256, 0, stream>>>(d_in[10], bo, nB, flag);

    dim3 gg(NROW / 16, DM / 64);   // 256 x 8 waves
    gemm_bias_bt<<<gg, 64, 0, stream>>>(qc, wq, bq, Qp, nullptr);
    gemm_bias_bt<<<gg, 64, 0, stream>>>(kc, wk, bk, Kp, nullptr);
    gemm_bias_bt<<<gg, 64, 0, stream>>>(vc, wv, bv, Vp, nullptr);

    dim3 ga(SEQ / 16, 16);          // 128 q-tiles x (B*H)
    attn_kernel<<<ga, 64, 0, stream>>>(Qp, Kp, Vp, Xp);

    gemm_bias_bt<<<gg, 64, 0, stream>>>(Xp, wo, bo, d_out, flag);
}

// Round 3
// 287.927 us; speedup vs baseline: 1.1962x; 1.1962x over previous
//
#include <hip/hip_runtime.h>
#include <hip/hip_bf16.h>

// MHA block: B=2, S=2048, D_MODEL=512, H=8, D_K=64.
// detect dtype -> convert to bf16 ws -> fused QKV GEMM (Q pre-scaled by 1/8,
// V written transposed [bh][d][s]) -> flash attention (64-key tiles, K-prefetch,
// DPP max-reduce, ones-MFMA row sums) -> output GEMM (stores f32/bf16 per flag).

typedef __attribute__((ext_vector_type(8))) short short8;   // 8 bf16 (4 VGPRs)
typedef __attribute__((ext_vector_type(4))) short short4v;  // 4 bf16 (8B)
typedef __attribute__((ext_vector_type(4))) float f32x4;    // MFMA 16x16 accum

#define DM 512
#define SEQ 2048
#define NROW 4096   // B * SEQ

__device__ __forceinline__ short f2bf_bits(float f) {
    __hip_bfloat16 h = __float2bfloat16(f);
    union { __hip_bfloat16 h; short s; } u; u.h = h; return u.s;
}
__device__ __forceinline__ float bf_bits2f(short s) {
    union { short s; __hip_bfloat16 h; } u; u.s = s; return __bfloat162float(u.h);
}

template <int CTRL>
__device__ __forceinline__ float dpp_rot(float x) {
    int i = __builtin_bit_cast(int, x);
    int r = __builtin_amdgcn_update_dpp(i, i, CTRL, 0xF, 0xF, false);
    return __builtin_bit_cast(float, r);
}
// reduce max over the 16-lane DPP row via row_ror 1,2,4,8
__device__ __forceinline__ float rowmax16(float mx) {
    mx = fmaxf(mx, dpp_rot<0x121>(mx));
    mx = fmaxf(mx, dpp_rot<0x122>(mx));
    mx = fmaxf(mx, dpp_rot<0x124>(mx));
    mx = fmaxf(mx, dpp_rot<0x128>(mx));
    return mx;
}

// ---------------------------------------------------------------------------
// Dtype detection (see round 1/2 notes): bf16-packed low halves land ~100% in
// [0x3000,0x4400) after masking sign; f32 mantissa bits ~16%. flag: 1 = f32.
__global__ void detect_dtype(const unsigned int* __restrict__ q, int* __restrict__ flag) {
    __shared__ int cnt;
    if (threadIdx.x == 0) cnt = 0;
    __syncthreads();
    int local = 0;
    for (int i = threadIdx.x; i < 1024; i += 256) {
        unsigned int lo = q[i] & 0x7FFFu;
        if (lo >= 0x3000u && lo < 0x4400u) local++;
    }
    atomicAdd(&cnt, local);
    __syncthreads();
    if (threadIdx.x == 0) *flag = (cnt < 512) ? 1 : 0;
}

// Fused conversion of all 11 tensors (f32->bf16 or bf16 copy), float4-vectorized.
struct ConvArgs { const void* src[11]; short* dst[11]; int n[11]; };
__global__ void convert_all(ConvArgs a, const int* __restrict__ flag) {
    const bool f32m = (*flag != 0);
    const int tid = blockIdx.x * 256 + threadIdx.x;
    const int stride = gridDim.x * 256;
    if (f32m) {
        for (int s = 0; s < 11; s++) {
            const float4* sp = (const float4*)a.src[s];
            short4v* dp = (short4v*)a.dst[s];
            const int n4 = a.n[s] >> 2;
            for (int i = tid; i < n4; i += stride) {
                float4 v = sp[i];
                short4v o;
                o[0] = f2bf_bits(v.x); o[1] = f2bf_bits(v.y);
                o[2] = f2bf_bits(v.z); o[3] = f2bf_bits(v.w);
                dp[i] = o;
            }
        }
    } else {
        for (int s = 0; s < 11; s++) {
            const short4v* sp = (const short4v*)a.src[s];
            short4v* dp = (short4v*)a.dst[s];
            const int n4 = a.n[s] >> 2;
            for (int i = tid; i < n4; i += stride) dp[i] = sp[i];
        }
    }
}

// ---------------------------------------------------------------------------
// Shared GEMM mainloop: 16(M)x64(N) tile per wave, K=512, 2-stage register
// prefetch. Layouts (m89/m91-verified): A m=lane&15,k=quad*8+j ;
// B n=lane&15,k=quad*8+j ; C row=quad*4+r,col=lane&15.
__device__ __forceinline__ void gemm_tile(const short* __restrict__ A,
                                          const short* __restrict__ W,
                                          int m0, int n0, int lane, f32x4 acc[4]) {
    const int rc = lane & 15, quad = lane >> 4;
    const short* Ap = A + (size_t)(m0 + rc) * DM + quad * 8;
    const short* W0 = W + (size_t)(n0 + rc) * DM + quad * 8;
    short8 aC, bC[4], aN, bN[4];
    aC = *(const short8*)Ap;
    #pragma unroll
    for (int nt = 0; nt < 4; nt++) bC[nt] = *(const short8*)(W0 + nt * 16 * DM);
    #pragma unroll
    for (int kk = 0; kk < 16; kk++) {
        if (kk < 15) {
            const int k1 = (kk + 1) * 32;
            aN = *(const short8*)(Ap + k1);
            #pragma unroll
            for (int nt = 0; nt < 4; nt++)
                bN[nt] = *(const short8*)(W0 + nt * 16 * DM + k1);
        }
        #pragma unroll
        for (int nt = 0; nt < 4; nt++)
            acc[nt] = __builtin_amdgcn_mfma_f32_16x16x32_bf16(aC, bC[nt], acc[nt], 0, 0, 0);
        aC = aN;
        #pragma unroll
        for (int nt = 0; nt < 4; nt++) bC[nt] = bN[nt];
    }
}

// Fused QKV projection. z=0: Q out, scaled by 0.125 (exact). z=1: K out.
// z=2: V out TRANSPOSED: Vt[((b*8+h)*64+d)*SEQ + s], packed short4 along s.
struct QKVArgs {
    const short* A[3]; const short* W[3]; const short* Bi[3];
    short* Cq; short* Ck; short* Cv;
};
__global__ __launch_bounds__(64, 4) void qkv_gemm(QKVArgs args) {
    const int z = blockIdx.z;
    const int lane = threadIdx.x;
    const int rc = lane & 15, quad = lane >> 4;
    const int m0 = blockIdx.x * 16, n0 = blockIdx.y * 64;

    f32x4 acc[4];
    #pragma unroll
    for (int nt = 0; nt < 4; nt++) acc[nt] = f32x4{0.f, 0.f, 0.f, 0.f};
    gemm_tile(args.A[z], args.W[z], m0, n0, lane, acc);
    const short* bias = args.Bi[z];

    if (z == 2) {
        short* Vt = args.Cv;
        const int h = n0 >> 6;          // n0 < 512
        const int b = m0 >> 11;
        const int sbase = m0 & 2047;
        #pragma unroll
        for (int nt = 0; nt < 4; nt++) {
            const int d = nt * 16 + rc;
            const float bv = bf_bits2f(bias[n0 + d]);
            short4v pk;
            #pragma unroll
            for (int r = 0; r < 4; r++) pk[r] = f2bf_bits(acc[nt][r] + bv);
            *(short4v*)(Vt + ((size_t)((b * 8 + h) * 64 + d)) * SEQ + sbase + quad * 4) = pk;
        }
    } else {
        short* C = (z == 0) ? args.Cq : args.Ck;
        const float qs = (z == 0) ? 0.125f : 1.0f;
        #pragma unroll
        for (int nt = 0; nt < 4; nt++) {
            const int col = n0 + nt * 16 + rc;
            const float bv = bf_bits2f(bias[col]);
            #pragma unroll
            for (int r = 0; r < 4; r++)
                C[(size_t)(m0 + quad * 4 + r) * DM + col] = f2bf_bits((acc[nt][r] + bv) * qs);
        }
    }
}

// Output projection; stores f32 or bf16 per runtime flag.
__global__ __launch_bounds__(64, 2) void out_gemm(
    const short* __restrict__ A, const short* __restrict__ W,
    const short* __restrict__ bias, void* __restrict__ Cout,
    const int* __restrict__ flag) {
    const int lane = threadIdx.x;
    const int rc = lane & 15, quad = lane >> 4;
    const int m0 = blockIdx.x * 16, n0 = blockIdx.y * 64;
    f32x4 acc[4];
    #pragma unroll
    for (int nt = 0; nt < 4; nt++) acc[nt] = f32x4{0.f, 0.f, 0.f, 0.f};
    gemm_tile(A, W, m0, n0, lane, acc);
    const bool f32out = (*flag != 0);
    #pragma unroll
    for (int nt = 0; nt < 4; nt++) {
        const int col = n0 + nt * 16 + rc;
        const float bv = bf_bits2f(bias[col]);
        #pragma unroll
        for (int r = 0; r < 4; r++) {
            const size_t idx = (size_t)(m0 + quad * 4 + r) * DM + col;
            const float val = acc[nt][r] + bv;
            if (f32out) ((float*)Cout)[idx] = val;
            else        ((short*)Cout)[idx] = f2bf_bits(val);
        }
    }
}

// ---------------------------------------------------------------------------
// Flash attention. One wave per (bh, 16-query tile). 64-key tiles.
// Q pre-scaled by 1/8. Score tile kt col rc <- K row k0+rc*4+kt, so lane's 4
// P-values are 4 consecutive LDS columns (one ds_write_b64 per row); overall
// key mapping is identity, so V is the plain transpose Vt[bh][d][s].
// K tiles double-buffered in registers; no __syncthreads (would drain vmcnt) —
// explicit s_waitcnt lgkmcnt(0) orders the single wave's LDS write->read.
__global__ __launch_bounds__(64, 2) void attn_kernel(
    const short* __restrict__ Q, const short* __restrict__ K,
    const short* __restrict__ Vt, short* __restrict__ O)
{
    const int lane = threadIdx.x;
    const int rc = lane & 15;
    const int quad = lane >> 4;
    const int bh = blockIdx.y;
    const size_t baseQ = (size_t)(bh >> 3) * SEQ * DM + (size_t)(bh & 7) * 64;
    const short* Qb = Q + baseQ;
    const short* Kb = K + baseQ;
    const short* Vb = Vt + (size_t)bh * 64 * SEQ;
    const int q0 = blockIdx.x * 16;

    short8 qa0 = *(const short8*)(Qb + (size_t)(q0 + rc) * DM + quad * 8);
    short8 qa1 = *(const short8*)(Qb + (size_t)(q0 + rc) * DM + 32 + quad * 8);

    short8 ones;
    #pragma unroll
    for (int j = 0; j < 8; j++) ones[j] = (short)0x3F80;   // bf16 1.0

    f32x4 o[4];
    #pragma unroll
    for (int dt = 0; dt < 4; dt++) o[dt] = f32x4{0.f, 0.f, 0.f, 0.f};
    float mrow[4], lrow[4];
    #pragma unroll
    for (int r = 0; r < 4; r++) { mrow[r] = -1e30f; lrow[r] = 0.f; }

    __shared__ __align__(16) short Plds[16 * 72];   // stride 72 shorts = 144B (16B-mult)

    short8 kA[4][2], kB[4][2];
    #pragma unroll
    for (int kt = 0; kt < 4; kt++)
        #pragma unroll
        for (int h = 0; h < 2; h++)
            kA[kt][h] = *(const short8*)(Kb + (size_t)(rc * 4 + kt) * DM + h * 32 + quad * 8);

    auto step = [&](int k0, short8 (&kc)[4][2], short8 (&kn)[4][2]) {
        // V fragments for this tile (contiguous from Vt) — issue early
        short8 vv[4][2];
        #pragma unroll
        for (int dt = 0; dt < 4; dt++)
            #pragma unroll
            for (int h = 0; h < 2; h++)
                vv[dt][h] = *(const short8*)(Vb + (size_t)(dt * 16 + rc) * SEQ + k0 + h * 32 + quad * 8);
        // K prefetch for next tile
        const int k0n = k0 + 64;
        if (k0n < SEQ) {
            #pragma unroll
            for (int kt = 0; kt < 4; kt++)
                #pragma unroll
                for (int h = 0; h < 2; h++)
                    kn[kt][h] = *(const short8*)(Kb + (size_t)(k0n + rc * 4 + kt) * DM + h * 32 + quad * 8);
        }
        // scores (Q pre-scaled)
        f32x4 s[4];
        #pragma unroll
        for (int kt = 0; kt < 4; kt++) {
            s[kt] = f32x4{0.f, 0.f, 0.f, 0.f};
            s[kt] = __builtin_amdgcn_mfma_f32_16x16x32_bf16(qa0, kc[kt][0], s[kt], 0, 0, 0);
            s[kt] = __builtin_amdgcn_mfma_f32_16x16x32_bf16(qa1, kc[kt][1], s[kt], 0, 0, 0);
        }
        // online softmax per row; P -> LDS (one b64 per row per lane)
        float alpha[4];
        #pragma unroll
        for (int r = 0; r < 4; r++) {
            float mx = fmaxf(fmaxf(s[0][r], s[1][r]), fmaxf(s[2][r], s[3][r]));
            mx = rowmax16(mx);
            const float mnew = fmaxf(mrow[r], mx);
            alpha[r] = __expf(mrow[r] - mnew);
            mrow[r] = mnew;
            short4v pk;
            #pragma unroll
            for (int kt = 0; kt < 4; kt++) pk[kt] = f2bf_bits(__expf(s[kt][r] - mnew));
            *(short4v*)(&Plds[(quad * 4 + r) * 72 + rc * 4]) = pk;
        }
        #pragma unroll
        for (int dt = 0; dt < 4; dt++)
            #pragma unroll
            for (int r = 0; r < 4; r++) o[dt][r] *= alpha[r];
        // LDS write -> read ordering for this single wave (no vmcnt drain)
        __asm__ __volatile__("" ::: "memory");
        __builtin_amdgcn_s_waitcnt(0xC07F);   // lgkmcnt(0) only
        __asm__ __volatile__("" ::: "memory");
        short8 pa0 = *(const short8*)(&Plds[rc * 72 + quad * 8]);
        short8 pa1 = *(const short8*)(&Plds[rc * 72 + 32 + quad * 8]);
        // row sums via ones-MFMA (replaces shuffle tree; consistent with bf16 P)
        f32x4 psum = f32x4{0.f, 0.f, 0.f, 0.f};
        psum = __builtin_amdgcn_mfma_f32_16x16x32_bf16(pa0, ones, psum, 0, 0, 0);
        psum = __builtin_amdgcn_mfma_f32_16x16x32_bf16(pa1, ones, psum, 0, 0, 0);
        #pragma unroll
        for (int dt = 0; dt < 4; dt++) {
            o[dt] = __builtin_amdgcn_mfma_f32_16x16x32_bf16(pa0, vv[dt][0], o[dt], 0, 0, 0);
            o[dt] = __builtin_amdgcn_mfma_f32_16x16x32_bf16(pa1, vv[dt][1], o[dt], 0, 0, 0);
        }
        #pragma unroll
        for (int r = 0; r < 4; r++) lrow[r] = lrow[r] * alpha[r] + psum[r];
    };

    for (int k0 = 0; k0 < SEQ; k0 += 128) {
        step(k0, kA, kB);
        step(k0 + 64, kB, kA);
    }

    float inv[4];
    #pragma unroll
    for (int r = 0; r < 4; r++) inv[r] = 1.0f / lrow[r];
    #pragma unroll
    for (int dt = 0; dt < 4; dt++)
        #pragma unroll
        for (int r = 0; r < 4; r++)
            O[baseQ + (size_t)(q0 + quad * 4 + r) * DM + dt * 16 + rc] = f2bf_bits(o[dt][r] * inv[r]);
}

// ---------------------------------------------------------------------------
extern "C" void kernel_launch(void* const* d_in, const int* in_sizes, int n_in,
                              void* d_out, int out_size, void* d_ws, size_t ws_size,
                              hipStream_t stream) {
    // setup_inputs order: q, v, k, w_q, b_q, w_k, b_k, w_v, b_v, w_o, b_o
    char* ws = (char*)d_ws;
    const size_t SEQB = (size_t)NROW * DM * sizeof(short);  // 4 MB
    const size_t WB   = (size_t)DM * DM * sizeof(short);    // 512 KB
    const size_t BB   = (size_t)DM * sizeof(short);         // 1 KB

    int* flag = (int*)ws;
    size_t off = 256;
    short* qc = (short*)(ws + off); off += SEQB;
    short* vc = (short*)(ws + off); off += SEQB;
    short* kc = (short*)(ws + off); off += SEQB;
    short* wq = (short*)(ws + off); off += WB;
    short* wk = (short*)(ws + off); off += WB;
    short* wv = (short*)(ws + off); off += WB;
    short* wo = (short*)(ws + off); off += WB;
    short* bq = (short*)(ws + off); off += BB;
    short* bk = (short*)(ws + off); off += BB;
    short* bv = (short*)(ws + off); off += BB;
    short* bo = (short*)(ws + off); off += BB;
    off = (off + 255) & ~(size_t)255;
    short* Qp  = (short*)(ws + off); off += SEQB;
    short* Kp  = (short*)(ws + off); off += SEQB;
    short* Vtp = (short*)(ws + off); off += SEQB;
    short* Xp  = (short*)(ws + off); off += SEQB;

    detect_dtype<<<1, 256, 0, stream>>>((const unsigned int*)d_in[0], flag);

    ConvArgs ca;
    const void* srcs[11] = {d_in[0], d_in[1], d_in[2], d_in[3], d_in[5], d_in[7],
                            d_in[9], d_in[4], d_in[6], d_in[8], d_in[10]};
    short* dsts[11] = {qc, vc, kc, wq, wk, wv, wo, bq, bk, bv, bo};
    int ns[11] = {NROW * DM, NROW * DM, NROW * DM, DM * DM, DM * DM, DM * DM,
                  DM * DM, DM, DM, DM, DM};
    for (int i = 0; i < 11; i++) { ca.src[i] = srcs[i]; ca.dst[i] = dsts[i]; ca.n[i] = ns[i]; }
    convert_all<<<1024, 256, 0, stream>>>(ca, flag);

    QKVArgs qa;
    qa.A[0] = qc; qa.A[1] = kc; qa.A[2] = vc;
    qa.W[0] = wq; qa.W[1] = wk; qa.W[2] = wv;
    qa.Bi[0] = bq; qa.Bi[1] = bk; qa.Bi[2] = bv;
    qa.Cq = Qp; qa.Ck = Kp; qa.Cv = Vtp;
    dim3 gg(NROW / 16, DM / 64, 3);
    qkv_gemm<<<gg, 64, 0, stream>>>(qa);

    dim3 ga(SEQ / 16, 16);
    attn_kernel<<<ga, 64, 0, stream>>>(Qp, Kp, Vtp, Xp);

    dim3 go(NROW / 16, DM / 64);
    out_gemm<<<go, 64, 0, stream>>>(Xp, wo, bo, d_out, flag);
}

// Round 4
// 166.369 us; speedup vs baseline: 2.0703x; 1.7307x over previous
//
#include <hip/hip_runtime.h>
#include <hip/hip_bf16.h>

// MHA block: B=2, S=2048, D_MODEL=512, H=8, D_K=64.
// detect dtype -> convert to bf16 ws -> fused QKV GEMM (LDS-staged, Q pre-scaled
// 1/8, V written transposed [bh][d][s]) -> flash attention (4-wave blocks, K/V
// tiles LDS double-buffered via global_load_lds, XOR-swizzled granules) ->
// output GEMM (stores f32/bf16 per flag).

typedef __attribute__((ext_vector_type(8))) short short8;   // 8 bf16 (4 VGPRs)
typedef __attribute__((ext_vector_type(4))) short short4v;  // 4 bf16 (8B)
typedef __attribute__((ext_vector_type(4))) float f32x4;    // MFMA 16x16 accum

#define DM 512
#define SEQ 2048
#define NROW 4096   // B * SEQ

__device__ __forceinline__ short f2bf_bits(float f) {
    __hip_bfloat16 h = __float2bfloat16(f);
    union { __hip_bfloat16 h; short s; } u; u.h = h; return u.s;
}
__device__ __forceinline__ float bf_bits2f(short s) {
    union { short s; __hip_bfloat16 h; } u; u.s = s; return __bfloat162float(u.h);
}

template <int CTRL>
__device__ __forceinline__ float dpp_rot(float x) {
    int i = __builtin_bit_cast(int, x);
    int r = __builtin_amdgcn_update_dpp(i, i, CTRL, 0xF, 0xF, false);
    return __builtin_bit_cast(float, r);
}
__device__ __forceinline__ float rowmax16(float mx) {   // max over 16-lane DPP row
    mx = fmaxf(mx, dpp_rot<0x121>(mx));
    mx = fmaxf(mx, dpp_rot<0x122>(mx));
    mx = fmaxf(mx, dpp_rot<0x124>(mx));
    mx = fmaxf(mx, dpp_rot<0x128>(mx));
    return mx;
}

// Async global->LDS, 16B per lane. LDS dest is wave-uniform base + lane*16;
// the GLOBAL source address is per-lane, so arbitrary 16B-granule permutations
// of the LDS layout are expressed on the source side.
__device__ __forceinline__ void gload_lds16(const void* src, void* lds_dst) {
    __builtin_amdgcn_global_load_lds(
        (const __attribute__((address_space(1))) unsigned int*)src,
        (__attribute__((address_space(3))) unsigned int*)lds_dst, 16, 0, 0);
}

// Stage a 64x64 bf16 tile (global row-major, row stride gstride shorts) into
// LDS with granule swizzle g = row*8 + (cb ^ (row&7)) (cb = 16B col-block).
// 256 threads, 2 granules each (8KB total). Read accessor for element
// [row][cb*8+j]: &lds[row*64 + ((cb ^ (row&7))*8)].
__device__ __forceinline__ void stage64(const short* __restrict__ gsrc, size_t gstride,
                                        short* lds, int wave, int lane) {
    #pragma unroll
    for (int i = 0; i < 2; i++) {
        const int g   = (i * 4 + wave) * 64 + lane;
        const int row = g >> 3;
        const int cb  = (g & 7) ^ (row & 7);
        gload_lds16(gsrc + (size_t)row * gstride + cb * 8,
                    lds + (size_t)(i * 4 + wave) * 512);   // wave-uniform base
    }
}

// ---------------------------------------------------------------------------
// Dtype detection: bf16-packed low halves of 32-bit words land ~100% in
// [0x3000,0x4400) after sign-mask; f32 mantissa bits ~16%. flag: 1 = f32.
__global__ void detect_dtype(const unsigned int* __restrict__ q, int* __restrict__ flag) {
    __shared__ int cnt;
    if (threadIdx.x == 0) cnt = 0;
    __syncthreads();
    int local = 0;
    for (int i = threadIdx.x; i < 1024; i += 256) {
        unsigned int lo = q[i] & 0x7FFFu;
        if (lo >= 0x3000u && lo < 0x4400u) local++;
    }
    atomicAdd(&cnt, local);
    __syncthreads();
    if (threadIdx.x == 0) *flag = (cnt < 512) ? 1 : 0;
}

// Fused conversion of all 11 tensors (f32->bf16 or bf16 copy), vectorized.
struct ConvArgs { const void* src[11]; short* dst[11]; int n[11]; };
__global__ void convert_all(ConvArgs a, const int* __restrict__ flag) {
    const bool f32m = (*flag != 0);
    const int tid = blockIdx.x * 256 + threadIdx.x;
    const int stride = gridDim.x * 256;
    if (f32m) {
        for (int s = 0; s < 11; s++) {
            const float4* sp = (const float4*)a.src[s];
            short4v* dp = (short4v*)a.dst[s];
            const int n4 = a.n[s] >> 2;
            for (int i = tid; i < n4; i += stride) {
                float4 v = sp[i];
                short4v o;
                o[0] = f2bf_bits(v.x); o[1] = f2bf_bits(v.y);
                o[2] = f2bf_bits(v.z); o[3] = f2bf_bits(v.w);
                dp[i] = o;
            }
        }
    } else {
        for (int s = 0; s < 11; s++) {
            const short4v* sp = (const short4v*)a.src[s];
            short4v* dp = (short4v*)a.dst[s];
            const int n4 = a.n[s] >> 2;
            for (int i = tid; i < n4; i += stride) dp[i] = sp[i];
        }
    }
}

// ---------------------------------------------------------------------------
// LDS-staged GEMM core: 256-thread block computes 64(M)x64(N), K=512, BK=64.
// Wave w does rows w*16..+15. m97-style 2-barrier staging loop.
// MFMA layouts (m89/m91-verified): A m=lane&15,k=quad*8+j ; B n=lane&15,k=... ;
// C row=quad*4+r, col=lane&15.
__device__ __forceinline__ void gemm_core(const short* __restrict__ A,
                                          const short* __restrict__ W,
                                          int m0, int n0,
                                          short* Alds, short* Blds,
                                          int wave, int lane, f32x4 acc[4]) {
    const int rc = lane & 15, quad = lane >> 4;
    const int arow = wave * 16 + rc;
    for (int k0 = 0; k0 < DM; k0 += 64) {
        __syncthreads();   // previous iteration's LDS reads complete
        stage64(A + (size_t)m0 * DM + k0, DM, Alds, wave, lane);
        stage64(W + (size_t)n0 * DM + k0, DM, Blds, wave, lane);
        __builtin_amdgcn_s_waitcnt(0x3F70);   // vmcnt(0)
        __syncthreads();
        #pragma unroll
        for (int h = 0; h < 2; h++) {
            short8 af = *(const short8*)&Alds[arow * 64 + (((quad + 4 * h) ^ (arow & 7)) * 8)];
            #pragma unroll
            for (int nt = 0; nt < 4; nt++) {
                const int brow = nt * 16 + rc;
                short8 bf = *(const short8*)&Blds[brow * 64 + (((quad + 4 * h) ^ (brow & 7)) * 8)];
                acc[nt] = __builtin_amdgcn_mfma_f32_16x16x32_bf16(af, bf, acc[nt], 0, 0, 0);
            }
        }
    }
}

// Fused QKV projection. z=0: Q out scaled by 0.125 (exact). z=1: K out.
// z=2: V out TRANSPOSED: Vt[((b*8+h)*64+d)*SEQ + s].
struct QKVArgs {
    const short* A[3]; const short* W[3]; const short* Bi[3];
    short* Cq; short* Ck; short* Cv;
};
__global__ __launch_bounds__(256, 4) void qkv_gemm(QKVArgs args) {
    __shared__ __align__(16) short Alds[64 * 64];
    __shared__ __align__(16) short Blds[64 * 64];
    const int z = blockIdx.z;
    const int wave = threadIdx.x >> 6, lane = threadIdx.x & 63;
    const int rc = lane & 15, quad = lane >> 4;
    const int m0 = blockIdx.x * 64, n0 = blockIdx.y * 64;

    f32x4 acc[4];
    #pragma unroll
    for (int nt = 0; nt < 4; nt++) acc[nt] = f32x4{0.f, 0.f, 0.f, 0.f};
    gemm_core(args.A[z], args.W[z], m0, n0, Alds, Blds, wave, lane, acc);

    const short* bias = args.Bi[z];
    const int mw = m0 + wave * 16;
    if (z == 2) {
        short* Vt = args.Cv;
        const int hh = n0 >> 6;
        const int b = mw >> 11;
        const int sbase = mw & 2047;
        #pragma unroll
        for (int nt = 0; nt < 4; nt++) {
            const int d = nt * 16 + rc;
            const float bv = bf_bits2f(bias[n0 + d]);
            short4v pk;
            #pragma unroll
            for (int r = 0; r < 4; r++) pk[r] = f2bf_bits(acc[nt][r] + bv);
            *(short4v*)(Vt + ((size_t)((b * 8 + hh) * 64 + d)) * SEQ + sbase + quad * 4) = pk;
        }
    } else {
        short* C = (z == 0) ? args.Cq : args.Ck;
        const float qs = (z == 0) ? 0.125f : 1.0f;
        #pragma unroll
        for (int nt = 0; nt < 4; nt++) {
            const int col = n0 + nt * 16 + rc;
            const float bv = bf_bits2f(bias[col]);
            #pragma unroll
            for (int r = 0; r < 4; r++)
                C[(size_t)(mw + quad * 4 + r) * DM + col] = f2bf_bits((acc[nt][r] + bv) * qs);
        }
    }
}

// Output projection; stores f32 or bf16 per runtime flag.
__global__ __launch_bounds__(256, 4) void out_gemm(
    const short* __restrict__ A, const short* __restrict__ W,
    const short* __restrict__ bias, void* __restrict__ Cout,
    const int* __restrict__ flag) {
    __shared__ __align__(16) short Alds[64 * 64];
    __shared__ __align__(16) short Blds[64 * 64];
    const int wave = threadIdx.x >> 6, lane = threadIdx.x & 63;
    const int rc = lane & 15, quad = lane >> 4;
    const int m0 = blockIdx.x * 64, n0 = blockIdx.y * 64;
    f32x4 acc[4];
    #pragma unroll
    for (int nt = 0; nt < 4; nt++) acc[nt] = f32x4{0.f, 0.f, 0.f, 0.f};
    gemm_core(A, W, m0, n0, Alds, Blds, wave, lane, acc);
    const bool f32out = (*flag != 0);
    const int mw = m0 + wave * 16;
    #pragma unroll
    for (int nt = 0; nt < 4; nt++) {
        const int col = n0 + nt * 16 + rc;
        const float bv = bf_bits2f(bias[col]);
        #pragma unroll
        for (int r = 0; r < 4; r++) {
            const size_t idx = (size_t)(mw + quad * 4 + r) * DM + col;
            const float val = acc[nt][r] + bv;
            if (f32out) ((float*)Cout)[idx] = val;
            else        ((short*)Cout)[idx] = f2bf_bits(val);
        }
    }
}

// ---------------------------------------------------------------------------
// Flash attention: 256-thread block = 4 waves = 64 queries (wave w: 16).
// K/V 64-key tiles shared via LDS, double-buffered: stage(next) overlaps
// compute(cur); raw s_barrier + manual vmcnt(4) keeps next-tile loads in
// flight across the barrier (no vmcnt(0) drain). Score col mapping: tile kt,
// col rc <- key rc*4+kt (identity overall), so P rows write as one b64 and
// A-frag reads line up with Vt. Q pre-scaled by 1/8 in projection.
__global__ __launch_bounds__(256, 2) void attn_kernel(
    const short* __restrict__ Q, const short* __restrict__ K,
    const short* __restrict__ Vt, short* __restrict__ O)
{
    __shared__ __align__(16) short Klds[2][64 * 64];
    __shared__ __align__(16) short Vlds[2][64 * 64];
    __shared__ __align__(16) short Plds[4][16 * 72];   // per-wave, stride 72 (bank-spread)

    const int wave = threadIdx.x >> 6, lane = threadIdx.x & 63;
    const int rc = lane & 15, quad = lane >> 4;
    const int bh = blockIdx.y;
    const size_t baseQ = (size_t)(bh >> 3) * SEQ * DM + (size_t)(bh & 7) * 64;
    const short* Qb = Q + baseQ;
    const short* Kb = K + baseQ;
    const short* Vb = Vt + (size_t)bh * 64 * SEQ;
    const int q0 = blockIdx.x * 64 + wave * 16;

    short8 qa0 = *(const short8*)(Qb + (size_t)(q0 + rc) * DM + quad * 8);
    short8 qa1 = *(const short8*)(Qb + (size_t)(q0 + rc) * DM + 32 + quad * 8);

    short8 ones;
    #pragma unroll
    for (int j = 0; j < 8; j++) ones[j] = (short)0x3F80;   // bf16 1.0

    f32x4 o[4];
    #pragma unroll
    for (int dt = 0; dt < 4; dt++) o[dt] = f32x4{0.f, 0.f, 0.f, 0.f};
    float mrow[4], lrow[4];
    #pragma unroll
    for (int r = 0; r < 4; r++) { mrow[r] = -1e30f; lrow[r] = 0.f; }
    short* Pw = &Plds[wave][0];

    // prologue: stage tile 0 into buffer 0 (2 K + 2 V glds per thread)
    stage64(Kb, DM, &Klds[0][0], wave, lane);
    stage64(Vb, SEQ, &Vlds[0][0], wave, lane);

    const int NIT = SEQ / 64;
    for (int it = 0; it < NIT; it++) {
        const int cur = it & 1;
        if (it + 1 < NIT) {
            const int k0n = (it + 1) * 64;
            stage64(Kb + (size_t)k0n * DM, DM, &Klds[1 - cur][0], wave, lane);
            stage64(Vb + k0n, SEQ, &Vlds[1 - cur][0], wave, lane);
            __builtin_amdgcn_s_waitcnt(0x3F74);   // vmcnt(4): cur's 4 loads done, next's in flight
        } else {
            __builtin_amdgcn_s_waitcnt(0x3F70);   // vmcnt(0)
        }
        __asm__ __volatile__("" ::: "memory");
        __builtin_amdgcn_s_barrier();              // cur tile visible to all waves
        __asm__ __volatile__("" ::: "memory");

        const short* Kt = &Klds[cur][0];
        const short* Vtl = &Vlds[cur][0];

        // scores: tile kt col rc <- LDS K row rc*4+kt
        f32x4 s[4];
        #pragma unroll
        for (int kt = 0; kt < 4; kt++) {
            const int row = rc * 4 + kt;
            short8 kf0 = *(const short8*)&Kt[row * 64 + ((quad ^ (row & 7)) * 8)];
            short8 kf1 = *(const short8*)&Kt[row * 64 + (((quad + 4) ^ (row & 7)) * 8)];
            s[kt] = f32x4{0.f, 0.f, 0.f, 0.f};
            s[kt] = __builtin_amdgcn_mfma_f32_16x16x32_bf16(qa0, kf0, s[kt], 0, 0, 0);
            s[kt] = __builtin_amdgcn_mfma_f32_16x16x32_bf16(qa1, kf1, s[kt], 0, 0, 0);
        }
        // online softmax per row; P -> per-wave LDS (one b64 per row per lane)
        float alpha[4];
        #pragma unroll
        for (int r = 0; r < 4; r++) {
            float mx = fmaxf(fmaxf(s[0][r], s[1][r]), fmaxf(s[2][r], s[3][r]));
            mx = rowmax16(mx);
            const float mnew = fmaxf(mrow[r], mx);
            alpha[r] = __expf(mrow[r] - mnew);
            mrow[r] = mnew;
            short4v pk;
            #pragma unroll
            for (int kt = 0; kt < 4; kt++) pk[kt] = f2bf_bits(__expf(s[kt][r] - mnew));
            *(short4v*)(&Pw[(quad * 4 + r) * 72 + rc * 4]) = pk;
        }
        #pragma unroll
        for (int dt = 0; dt < 4; dt++)
            #pragma unroll
            for (int r = 0; r < 4; r++) o[dt][r] *= alpha[r];

        __builtin_amdgcn_s_waitcnt(0xC07F);   // lgkmcnt(0): P write->read, same wave
        short8 pa0 = *(const short8*)(&Pw[rc * 72 + quad * 8]);
        short8 pa1 = *(const short8*)(&Pw[rc * 72 + 32 + quad * 8]);

        f32x4 psum = f32x4{0.f, 0.f, 0.f, 0.f};
        psum = __builtin_amdgcn_mfma_f32_16x16x32_bf16(pa0, ones, psum, 0, 0, 0);
        psum = __builtin_amdgcn_mfma_f32_16x16x32_bf16(pa1, ones, psum, 0, 0, 0);
        #pragma unroll
        for (int dt = 0; dt < 4; dt++) {
            const int row = dt * 16 + rc;   // V LDS row = d
            short8 vv0 = *(const short8*)&Vtl[row * 64 + ((quad ^ (row & 7)) * 8)];
            short8 vv1 = *(const short8*)&Vtl[row * 64 + (((quad + 4) ^ (row & 7)) * 8)];
            o[dt] = __builtin_amdgcn_mfma_f32_16x16x32_bf16(pa0, vv0, o[dt], 0, 0, 0);
            o[dt] = __builtin_amdgcn_mfma_f32_16x16x32_bf16(pa1, vv1, o[dt], 0, 0, 0);
        }
        #pragma unroll
        for (int r = 0; r < 4; r++) lrow[r] = lrow[r] * alpha[r] + psum[r];

        __asm__ __volatile__("" ::: "memory");
        __builtin_amdgcn_s_barrier();   // all waves done reading cur before overwrite
        __asm__ __volatile__("" ::: "memory");
    }

    float inv[4];
    #pragma unroll
    for (int r = 0; r < 4; r++) inv[r] = 1.0f / lrow[r];
    #pragma unroll
    for (int dt = 0; dt < 4; dt++)
        #pragma unroll
        for (int r = 0; r < 4; r++)
            O[baseQ + (size_t)(q0 + quad * 4 + r) * DM + dt * 16 + rc] = f2bf_bits(o[dt][r] * inv[r]);
}

// ---------------------------------------------------------------------------
extern "C" void kernel_launch(void* const* d_in, const int* in_sizes, int n_in,
                              void* d_out, int out_size, void* d_ws, size_t ws_size,
                              hipStream_t stream) {
    // setup_inputs order: q, v, k, w_q, b_q, w_k, b_k, w_v, b_v, w_o, b_o
    char* ws = (char*)d_ws;
    const size_t SEQB = (size_t)NROW * DM * sizeof(short);  // 4 MB
    const size_t WB   = (size_t)DM * DM * sizeof(short);    // 512 KB
    const size_t BB   = (size_t)DM * sizeof(short);         // 1 KB

    int* flag = (int*)ws;
    size_t off = 256;
    short* qc = (short*)(ws + off); off += SEQB;
    short* vc = (short*)(ws + off); off += SEQB;
    short* kc = (short*)(ws + off); off += SEQB;
    short* wq = (short*)(ws + off); off += WB;
    short* wk = (short*)(ws + off); off += WB;
    short* wv = (short*)(ws + off); off += WB;
    short* wo = (short*)(ws + off); off += WB;
    short* bq = (short*)(ws + off); off += BB;
    short* bk = (short*)(ws + off); off += BB;
    short* bv = (short*)(ws + off); off += BB;
    short* bo = (short*)(ws + off); off += BB;
    off = (off + 255) & ~(size_t)255;
    short* Qp  = (short*)(ws + off); off += SEQB;
    short* Kp  = (short*)(ws + off); off += SEQB;
    short* Vtp = (short*)(ws + off); off += SEQB;
    short* Xp  = (short*)(ws + off); off += SEQB;

    detect_dtype<<<1, 256, 0, stream>>>((const unsigned int*)d_in[0], flag);

    ConvArgs ca;
    const void* srcs[11] = {d_in[0], d_in[1], d_in[2], d_in[3], d_in[5], d_in[7],
                            d_in[9], d_in[4], d_in[6], d_in[8], d_in[10]};
    short* dsts[11] = {qc, vc, kc, wq, wk, wv, wo, bq, bk, bv, bo};
    int ns[11] = {NROW * DM, NROW * DM, NROW * DM, DM * DM, DM * DM, DM * DM,
                  DM * DM, DM, DM, DM, DM};
    for (int i = 0; i < 11; i++) { ca.src[i] = srcs[i]; ca.dst[i] = dsts[i]; ca.n[i] = ns[i]; }
    convert_all<<<1024, 256, 0, stream>>>(ca, flag);

    QKVArgs qa;
    qa.A[0] = qc; qa.A[1] = kc; qa.A[2] = vc;
    qa.W[0] = wq; qa.W[1] = wk; qa.W[2] = wv;
    qa.Bi[0] = bq; qa.Bi[1] = bk; qa.Bi[2] = bv;
    qa.Cq = Qp; qa.Ck = Kp; qa.Cv = Vtp;
    dim3 gg(NROW / 64, DM / 64, 3);   // 64 x 8 x 3 = 1536 blocks
    qkv_gemm<<<gg, 256, 0, stream>>>(qa);

    dim3 ga(SEQ / 64, 16);            // 32 x 16 = 512 blocks
    attn_kernel<<<ga, 256, 0, stream>>>(Qp, Kp, Vtp, Xp);

    dim3 go(NROW / 64, DM / 64);      // 512 blocks
    out_gemm<<<go, 256, 0, stream>>>(Xp, wo, bo, d_out, flag);
}